// Round 4
// baseline (89.345 us; speedup 1.0000x reference)
//
#include <hip/hip_runtime.h>

// Gram matrix lower-tri extraction: out[b, i*(i-1)/2 + j] = sum_d X[b,i,d]*X[b,j,d], i>j
// B=8192, N=64, D=128, fp32 in/out. bf16 MFMA (16x16x32), one wave per sample, no LDS.
//
// R3 = R2 with the compile fix: nontemporal load through a clang ext_vector
// pointer (f32x4), not HIP's float4 class type.
// (1) __launch_bounds__(256,4) caps VGPR at 128 -> 4 waves/SIMD;
// (2) nontemporal loads+stores (zero-reuse streams skip cache thrash).

typedef __attribute__((ext_vector_type(8))) short bf16x8;
typedef __attribute__((ext_vector_type(4))) float f32x4;

__device__ inline short f2bf(float f) {
    // round-to-nearest-even fp32 -> bf16 (inputs are finite normals)
    unsigned int u = __float_as_uint(f);
    u += 0x7fffu + ((u >> 16) & 1u);
    return (short)(u >> 16);
}

__global__ __launch_bounds__(256, 4) void gram_tril_kernel(const float* __restrict__ X,
                                                           float* __restrict__ out) {
    const int wave = threadIdx.x >> 6;
    const int lane = threadIdx.x & 63;
    const int b = blockIdx.x * 4 + wave;

    const float* __restrict__ Xb = X + (size_t)b * (64 * 128);
    const int lr = lane & 15;   // row within 16-row block (fixed by MFMA layout)
    const int lg = lane >> 4;   // quarter-selector within each 64-B chunk

    bf16x8 frag[4][4];
#pragma unroll
    for (int ti = 0; ti < 4; ++ti) {
        const float* rowp = Xb + (size_t)(ti * 16 + lr) * 128 + lg * 4;
#pragma unroll
        for (int q = 0; q < 8; ++q) {
            // wave footprint of this load: rows 0..15, bytes [q*64, q*64+64) each
            const f32x4 a = __builtin_nontemporal_load((const f32x4*)(rowp + q * 16));
            const int ks = q >> 1;
            const int h = (q & 1) * 4;
            frag[ti][ks][h + 0] = f2bf(a.x);
            frag[ti][ks][h + 1] = f2bf(a.y);
            frag[ti][ks][h + 2] = f2bf(a.z);
            frag[ti][ks][h + 3] = f2bf(a.w);
        }
    }

    float* __restrict__ ob = out + (size_t)b * 2016;

    // 10 lower-tri tiles (ti >= tj); diagonal tiles masked to strict-lower.
#pragma unroll
    for (int ti = 0; ti < 4; ++ti) {
#pragma unroll
        for (int tj = 0; tj <= ti; ++tj) {
            f32x4 acc = {0.f, 0.f, 0.f, 0.f};
#pragma unroll
            for (int ks = 0; ks < 4; ++ks) {
                acc = __builtin_amdgcn_mfma_f32_16x16x32_bf16(frag[ti][ks], frag[tj][ks],
                                                              acc, 0, 0, 0);
            }
            const int j = tj * 16 + lr;  // C/D: col = lane&15
#pragma unroll
            for (int r = 0; r < 4; ++r) {
                const int i = ti * 16 + lg * 4 + r;  // C/D: row = (lane>>4)*4 + reg
                if (ti > tj || i > j) {
                    __builtin_nontemporal_store(acc[r], &ob[(i * (i - 1)) / 2 + j]);
                }
            }
        }
    }
}

extern "C" void kernel_launch(void* const* d_in, const int* in_sizes, int n_in,
                              void* d_out, int out_size, void* d_ws, size_t ws_size,
                              hipStream_t stream) {
    const float* X = (const float*)d_in[0];
    float* out = (float*)d_out;
    const int B = in_sizes[0] / (64 * 128);  // 8192
    const int blocks = B / 4;                // 4 waves/block, 1 sample/wave
    gram_tril_kernel<<<blocks, 256, 0, stream>>>(X, out);
}

// Round 5
// 66.814 us; speedup vs baseline: 1.3372x; 1.3372x over previous
//
#include <hip/hip_runtime.h>

// Gram matrix lower-tri extraction: out[b, i*(i-1)/2 + j] = sum_d X[b,i,d]*X[b,j,d], i>j
// B=8192, N=64, D=128, fp32 in/out. bf16 MFMA (16x16x32), one wave per sample, no LDS.
//
// R4: single-variable experiment vs R1 — add ONLY __launch_bounds__(256,4)
// (cap VGPR at 128 -> 4 waves/SIMD). No nontemporal ops (R3 bundled both and
// regressed; NT stores suspected of breaking L2 write-coalescing of our 64-B
// row segments).

typedef __attribute__((ext_vector_type(8))) short bf16x8;
typedef __attribute__((ext_vector_type(4))) float f32x4;

__device__ inline short f2bf(float f) {
    // round-to-nearest-even fp32 -> bf16 (inputs are finite normals)
    unsigned int u = __float_as_uint(f);
    u += 0x7fffu + ((u >> 16) & 1u);
    return (short)(u >> 16);
}

__global__ __launch_bounds__(256, 4) void gram_tril_kernel(const float* __restrict__ X,
                                                           float* __restrict__ out) {
    const int wave = threadIdx.x >> 6;
    const int lane = threadIdx.x & 63;
    const int b = blockIdx.x * 4 + wave;

    const float* __restrict__ Xb = X + (size_t)b * (64 * 128);
    const int lr = lane & 15;   // row within 16-row block (fixed by MFMA layout)
    const int lg = lane >> 4;   // quarter-selector within each 64-B chunk

    bf16x8 frag[4][4];
#pragma unroll
    for (int ti = 0; ti < 4; ++ti) {
        const float* rowp = Xb + (size_t)(ti * 16 + lr) * 128 + lg * 4;
#pragma unroll
        for (int q = 0; q < 8; ++q) {
            // wave footprint of this load: rows 0..15, bytes [q*64, q*64+64) each
            const float4 a = *(const float4*)(rowp + q * 16);
            const int ks = q >> 1;
            const int h = (q & 1) * 4;
            frag[ti][ks][h + 0] = f2bf(a.x);
            frag[ti][ks][h + 1] = f2bf(a.y);
            frag[ti][ks][h + 2] = f2bf(a.z);
            frag[ti][ks][h + 3] = f2bf(a.w);
        }
    }

    float* __restrict__ ob = out + (size_t)b * 2016;

    // 10 lower-tri tiles (ti >= tj); diagonal tiles masked to strict-lower.
#pragma unroll
    for (int ti = 0; ti < 4; ++ti) {
#pragma unroll
        for (int tj = 0; tj <= ti; ++tj) {
            f32x4 acc = {0.f, 0.f, 0.f, 0.f};
#pragma unroll
            for (int ks = 0; ks < 4; ++ks) {
                acc = __builtin_amdgcn_mfma_f32_16x16x32_bf16(frag[ti][ks], frag[tj][ks],
                                                              acc, 0, 0, 0);
            }
            const int j = tj * 16 + lr;  // C/D: col = lane&15
#pragma unroll
            for (int r = 0; r < 4; ++r) {
                const int i = ti * 16 + lg * 4 + r;  // C/D: row = (lane>>4)*4 + reg
                if (ti > tj || i > j) {
                    ob[(i * (i - 1)) / 2 + j] = acc[r];
                }
            }
        }
    }
}

extern "C" void kernel_launch(void* const* d_in, const int* in_sizes, int n_in,
                              void* d_out, int out_size, void* d_ws, size_t ws_size,
                              hipStream_t stream) {
    const float* X = (const float*)d_in[0];
    float* out = (float*)d_out;
    const int B = in_sizes[0] / (64 * 128);  // 8192
    const int blocks = B / 4;                // 4 waves/block, 1 sample/wave
    gram_tril_kernel<<<blocks, 256, 0, stream>>>(X, out);
}

// Round 6
// 64.753 us; speedup vs baseline: 1.3798x; 1.0318x over previous
//
#include <hip/hip_runtime.h>

// Gram matrix lower-tri extraction: out[b, i*(i-1)/2 + j] = sum_d X[b,i,d]*X[b,j,d], i>j
// B=8192, N=64, D=128, fp32 in/out. bf16 MFMA (16x16x32), one wave per sample.
//
// R5: single-variable experiment vs R4 — replace the 40 exec-masked scalar
// global stores (unaligned 64-B row segments) with an LDS-staged output:
// scatter the packed-triangular values into an 8-KB per-wave LDS buffer,
// then stream it out as aligned dwordx4 stores (1 KB per instruction).
// Tests whether partial-line scattered writes were degrading DRAM efficiency.

typedef __attribute__((ext_vector_type(8))) short bf16x8;
typedef __attribute__((ext_vector_type(4))) float f32x4;

__device__ inline short f2bf(float f) {
    // round-to-nearest-even fp32 -> bf16 (inputs are finite normals)
    unsigned int u = __float_as_uint(f);
    u += 0x7fffu + ((u >> 16) & 1u);
    return (short)(u >> 16);
}

__global__ __launch_bounds__(256) void gram_tril_kernel(const float* __restrict__ X,
                                                        float* __restrict__ out) {
    __shared__ float obuf[4][2016];  // 8064 B per wave, 32 KB per block

    const int wave = threadIdx.x >> 6;
    const int lane = threadIdx.x & 63;
    const int b = blockIdx.x * 4 + wave;

    const float* __restrict__ Xb = X + (size_t)b * (64 * 128);
    const int lr = lane & 15;   // row within 16-row block (fixed by MFMA layout)
    const int lg = lane >> 4;   // quarter-selector within each 64-B chunk

    bf16x8 frag[4][4];
#pragma unroll
    for (int ti = 0; ti < 4; ++ti) {
        const float* rowp = Xb + (size_t)(ti * 16 + lr) * 128 + lg * 4;
#pragma unroll
        for (int q = 0; q < 8; ++q) {
            // wave footprint of this load: rows 0..15, bytes [q*64, q*64+64) each
            const float4 a = *(const float4*)(rowp + q * 16);
            const int ks = q >> 1;
            const int h = (q & 1) * 4;
            frag[ti][ks][h + 0] = f2bf(a.x);
            frag[ti][ks][h + 1] = f2bf(a.y);
            frag[ti][ks][h + 2] = f2bf(a.z);
            frag[ti][ks][h + 3] = f2bf(a.w);
        }
    }

    float* wbuf = obuf[wave];

    // 10 lower-tri tiles (ti >= tj); diagonal tiles masked to strict-lower.
    // Scatter results into the per-wave LDS buffer (cheap there).
#pragma unroll
    for (int ti = 0; ti < 4; ++ti) {
#pragma unroll
        for (int tj = 0; tj <= ti; ++tj) {
            f32x4 acc = {0.f, 0.f, 0.f, 0.f};
#pragma unroll
            for (int ks = 0; ks < 4; ++ks) {
                acc = __builtin_amdgcn_mfma_f32_16x16x32_bf16(frag[ti][ks], frag[tj][ks],
                                                              acc, 0, 0, 0);
            }
            const int j = tj * 16 + lr;  // C/D: col = lane&15
#pragma unroll
            for (int r = 0; r < 4; ++r) {
                const int i = ti * 16 + lg * 4 + r;  // C/D: row = (lane>>4)*4 + reg
                if (ti > tj || i > j) {
                    wbuf[(i * (i - 1)) / 2 + j] = acc[r];
                }
            }
        }
    }

    // Same-wave LDS write->read ordering (no cross-wave sharing, no barrier).
    asm volatile("s_waitcnt lgkmcnt(0)" ::: "memory");

    // Stream out: 7 full chunks of 256 floats (1 KB per instruction, aligned)
    // + tail of 224 floats (lanes 0..55). 2016 = 7*256 + 224.
    float* __restrict__ ob = out + (size_t)b * 2016;
#pragma unroll
    for (int c = 0; c < 7; ++c) {
        const f32x4 v = *(const f32x4*)(wbuf + c * 256 + lane * 4);
        *(f32x4*)(ob + c * 256 + lane * 4) = v;
    }
    if (lane < 56) {
        const f32x4 v = *(const f32x4*)(wbuf + 1792 + lane * 4);
        *(f32x4*)(ob + 1792 + lane * 4) = v;
    }
}

extern "C" void kernel_launch(void* const* d_in, const int* in_sizes, int n_in,
                              void* d_out, int out_size, void* d_ws, size_t ws_size,
                              hipStream_t stream) {
    const float* X = (const float*)d_in[0];
    float* out = (float*)d_out;
    const int B = in_sizes[0] / (64 * 128);  // 8192
    const int blocks = B / 4;                // 4 waves/block, 1 sample/wave
    gram_tril_kernel<<<blocks, 256, 0, stream>>>(X, out);
}